// Round 1
// baseline (712.886 us; speedup 1.0000x reference)
//
#include <hip/hip_runtime.h>
#include <hip/hip_bf16.h>

// Problem constants (CrossNetMixFuxiCTR): B=16384, D=2048, L=3, E=8, R=64
#define BDIM 16384
#define DDIM 2048
#define LNUM 3
#define ENUM 8
#define RNUM 64
#define NP 24            // L*E (l,e) pairs

// GEMM tile
#define BM 128
#define BK 32

typedef _Float16 f16x8 __attribute__((ext_vector_type(8)));
typedef _Float16 f16x4 __attribute__((ext_vector_type(4)));
typedef float f32x4 __attribute__((ext_vector_type(4)));

// ---------------- convert X0 (fp32) -> X0h (f16) ----------------
__global__ void cvt_x_kernel(const float* __restrict__ X, _Float16* __restrict__ Xh) {
    size_t i = (size_t)blockIdx.x * blockDim.x + threadIdx.x;   // float4 index
    float4 v = ((const float4*)X)[i];
    f16x4 h = { (_Float16)v.x, (_Float16)v.y, (_Float16)v.z, (_Float16)v.w };
    ((f16x4*)Xh)[i] = h;
}

// ------- convert U,V -> Wh f16, layout [p=24][128 rows: 64 U then 64 V][D] -------
__global__ void cvt_w_kernel(const float* __restrict__ U, const float* __restrict__ V,
                             _Float16* __restrict__ Wh) {
    size_t f = (size_t)blockIdx.x * blockDim.x + threadIdx.x;   // float4 index
    size_t elem = f * 4;
    int d   = (int)(elem & (DDIM - 1));
    int row = (int)((elem >> 11) & 127);   // /2048 % 128
    int p   = (int)(elem >> 18);           // /(2048*128)
    const float* src = (row < 64)
        ? (U + ((size_t)(p * 64 + row) * DDIM + d))
        : (V + ((size_t)(p * 64 + (row - 64)) * DDIM + d));
    float4 v = *(const float4*)src;
    f16x4 h = { (_Float16)v.x, (_Float16)v.y, (_Float16)v.z, (_Float16)v.w };
    ((f16x4*)Wh)[f] = h;
}

// ---------------- fp32 gate logits: G[j][b] = X0[b] . Wg[j]  (j = l*8+e) ----------------
// one wave handles 4 rows (shares each Wg load across 4 rows); block = 4 waves = 16 rows
__global__ void gate_kernel(const float* __restrict__ X0, const float* __restrict__ Wg,
                            float* __restrict__ G) {
    const int wave = threadIdx.x >> 6;
    const int lane = threadIdx.x & 63;
    const int b0 = (blockIdx.x * 4 + wave) * 4;
    float acc[4][NP];
#pragma unroll
    for (int i = 0; i < 4; ++i)
#pragma unroll
        for (int j = 0; j < NP; ++j) acc[i][j] = 0.f;
    const float* xp = X0 + (size_t)b0 * DDIM;
    for (int d = lane; d < DDIM; d += 64) {
        float x[4];
#pragma unroll
        for (int i = 0; i < 4; ++i) x[i] = xp[(size_t)i * DDIM + d];
#pragma unroll
        for (int j = 0; j < NP; ++j) {
            float w = Wg[(size_t)j * DDIM + d];
#pragma unroll
            for (int i = 0; i < 4; ++i) acc[i][j] += x[i] * w;
        }
    }
#pragma unroll
    for (int i = 0; i < 4; ++i)
#pragma unroll
        for (int j = 0; j < NP; ++j) {
            float v = acc[i][j];
            v += __shfl_xor(v, 1);
            v += __shfl_xor(v, 2);
            v += __shfl_xor(v, 4);
            v += __shfl_xor(v, 8);
            v += __shfl_xor(v, 16);
            v += __shfl_xor(v, 32);
            if (lane == 0) G[(size_t)j * BDIM + (b0 + i)] = v;
        }
}

// ---------------- MFMA GEMM + in-wave bilinear reduction ----------------
// Block: 256 thr (4 waves). Tile: 128 rows x 128 cols (one (l,e): cols 0-63 = PU, 64-127 = PV).
// Wave w computes rows [w*32, w*32+32) x all 128 cols (2x8 tiles of 16x16x32 f16 MFMA).
// T[p][m] = sum_r PU[m][r]*PV[m][r] = in-lane sum over ni of acc[mi][ni]*acc[mi][ni+4]
//           + butterfly over lane&15. Never materializes P.
__global__ __launch_bounds__(256) void gemm_t_kernel(
    const _Float16* __restrict__ Ah,   // [BDIM][DDIM] f16
    const _Float16* __restrict__ Bh,   // [NP][128][DDIM] f16
    float* __restrict__ T)             // [NP][BDIM]
{
    const int p    = blockIdx.y;
    const int m0   = blockIdx.x * BM;
    const int tid  = (int)threadIdx.x;
    const int wave = tid >> 6;
    const int lane = tid & 63;
    const int mlane = lane & 15;
    const int quad  = lane >> 4;

    __shared__ _Float16 As[BM * BK];    // 8 KB
    __shared__ _Float16 Bs[128 * BK];   // 8 KB

    const _Float16* Bp = Bh + (size_t)p * 128 * DDIM;

    f32x4 acc[2][8];
#pragma unroll
    for (int i = 0; i < 2; ++i)
#pragma unroll
        for (int j = 0; j < 8; ++j) acc[i][j] = (f32x4){0.f, 0.f, 0.f, 0.f};

    const int srow = lane >> 2;          // 0..15 within 16-row chunk
    const int scol = (lane & 3) * 8;     // f16 col 0/8/16/24

    for (int k0 = 0; k0 < DDIM; k0 += BK) {
        __syncthreads();   // previous iter's LDS reads done before overwrite
#pragma unroll
        for (int q = 0; q < 2; ++q) {
            int r = wave * 32 + q * 16;                 // chunk base row
            const _Float16* ga = Ah + (size_t)(m0 + r + srow) * DDIM + k0 + scol;
            __builtin_amdgcn_global_load_lds(
                (const __attribute__((address_space(1))) void*)ga,
                (__attribute__((address_space(3))) void*)&As[r * BK], 16, 0, 0);
            const _Float16* gb = Bp + (size_t)(r + srow) * DDIM + k0 + scol;
            __builtin_amdgcn_global_load_lds(
                (const __attribute__((address_space(1))) void*)gb,
                (__attribute__((address_space(3))) void*)&Bs[r * BK], 16, 0, 0);
        }
        __syncthreads();   // drains vmcnt -> staged data visible

        f16x8 aF[2], bF[8];
#pragma unroll
        for (int mi = 0; mi < 2; ++mi)
            aF[mi] = *(const f16x8*)&As[(wave * 32 + mi * 16 + mlane) * BK + quad * 8];
#pragma unroll
        for (int ni = 0; ni < 8; ++ni)
            bF[ni] = *(const f16x8*)&Bs[(ni * 16 + mlane) * BK + quad * 8];
#pragma unroll
        for (int mi = 0; mi < 2; ++mi)
#pragma unroll
            for (int ni = 0; ni < 8; ++ni)
                acc[mi][ni] = __builtin_amdgcn_mfma_f32_16x16x32_f16(
                    aF[mi], bF[ni], acc[mi][ni], 0, 0, 0);
    }

    // C/D layout: col = lane&15, row = quad*4 + reg. PU col r at ni=r/16, PV at ni+4 (same lane).
#pragma unroll
    for (int mi = 0; mi < 2; ++mi) {
#pragma unroll
        for (int j = 0; j < 4; ++j) {
            float tp = 0.f;
#pragma unroll
            for (int ni = 0; ni < 4; ++ni)
                tp += acc[mi][ni][j] * acc[mi][ni + 4][j];
            tp += __shfl_xor(tp, 1);
            tp += __shfl_xor(tp, 2);
            tp += __shfl_xor(tp, 4);
            tp += __shfl_xor(tp, 8);
            if (mlane == 0) {
                int m = wave * 32 + mi * 16 + quad * 4 + j;
                T[(size_t)p * BDIM + (m0 + m)] = tp;
            }
        }
    }
}

// ---------------- per-row scalar recurrence + scaled write-out ----------------
__global__ void epilogue_kernel(const float* __restrict__ X0,
                                const float* __restrict__ T,
                                const float* __restrict__ G,
                                const float* __restrict__ bg,
                                float* __restrict__ out) {
    __shared__ float s_sh[16];
    const int b0 = blockIdx.x * 16;
    const int tid = (int)threadIdx.x;
    if (tid < 16) {
        int b = b0 + tid;
        float s = 1.f;
#pragma unroll
        for (int l = 0; l < LNUM; ++l) {
            float logit[ENUM];
            float mx = -1e30f;
#pragma unroll
            for (int e = 0; e < ENUM; ++e) {
                int j = l * ENUM + e;
                float g = s * G[(size_t)j * BDIM + b] + bg[j];
                logit[e] = g;
                mx = fmaxf(mx, g);
            }
            float den = 0.f, num = 0.f;
            float s2 = s * s;
#pragma unroll
            for (int e = 0; e < ENUM; ++e) {
                int j = l * ENUM + e;
                float w = __expf(logit[e] - mx);
                den += w;
                num += w * (s2 * T[(size_t)j * BDIM + b]);
            }
            s += num / den;
        }
        s_sh[tid] = s;
    }
    __syncthreads();
    const int nf4 = DDIM / 4;   // 512
    for (int idx = tid; idx < 16 * nf4; idx += 256) {
        int r = idx >> 9;
        int c = idx & (nf4 - 1);
        float s = s_sh[r];
        float4 x = ((const float4*)(X0 + (size_t)(b0 + r) * DDIM))[c];
        x.x *= s; x.y *= s; x.z *= s; x.w *= s;
        ((float4*)(out + (size_t)(b0 + r) * DDIM))[c] = x;
    }
}

extern "C" void kernel_launch(void* const* d_in, const int* in_sizes, int n_in,
                              void* d_out, int out_size, void* d_ws, size_t ws_size,
                              hipStream_t stream) {
    const float* X0 = (const float*)d_in[0];
    const float* U  = (const float*)d_in[1];
    const float* V  = (const float*)d_in[2];
    const float* Wg = (const float*)d_in[3];
    const float* bg = (const float*)d_in[4];
    float* out = (float*)d_out;

    // workspace layout (needs ~82.8 MB)
    char* ws = (char*)d_ws;
    _Float16* X0h = (_Float16*)ws;                                   // 16384*2048*2 = 67108864
    _Float16* Wh  = (_Float16*)(ws + 67108864ull);                   // 24*128*2048*2 = 12582912
    float* T      = (float*)(ws + 67108864ull + 12582912ull);        // 24*16384*4 = 1572864
    float* G      = (float*)(ws + 67108864ull + 12582912ull + 1572864ull);

    cvt_x_kernel<<<dim3((BDIM * DDIM / 4) / 256), dim3(256), 0, stream>>>(X0, X0h);
    cvt_w_kernel<<<dim3((NP * 128 * DDIM / 4) / 256), dim3(256), 0, stream>>>(U, V, Wh);
    gate_kernel<<<dim3(BDIM / 16), dim3(256), 0, stream>>>(X0, Wg, G);
    gemm_t_kernel<<<dim3(BDIM / BM, NP), dim3(256), 0, stream>>>(X0h, Wh, T);
    epilogue_kernel<<<dim3(BDIM / 16), dim3(256), 0, stream>>>(X0, T, G, bg, out);
}